// Round 4
// baseline (142.787 us; speedup 1.0000x reference)
//
#include <hip/hip_runtime.h>

// One thread = one row. Matmuls via v_dot2_f32_f16 (2 f16 MACs/instr, f32
// accum) with weights pre-packed+activation-scaled into d_ws as f16x2.
// State updated IN PLACE (left-to-right, carrying old-prev in 6 regs) to
// halve live registers vs the round-3 ping-pong, and amdgpu_waves_per_eu(4,4)
// pins the allocator at 4 waves/EU so it uses up to 128 VGPRs instead of
// spilling (round 3: VGPR=64 chosen, 60 MB of scratch traffic).

typedef _Float16 half2v __attribute__((ext_vector_type(2)));

__device__ __forceinline__ float fexp2(float x) { return __builtin_amdgcn_exp2f(x); }
__device__ __forceinline__ float frcp(float x)  { return __builtin_amdgcn_rcpf(x); }
__device__ __forceinline__ float fdot2(half2v a, half2v b, float c) {
    return __builtin_amdgcn_fdot2(a, b, c, false);
}
__device__ __forceinline__ half2v pkh(float a, float b) {
    return half2v{(_Float16)a, (_Float16)b};
}
__device__ __forceinline__ unsigned pku(float a, float b) {
    union { unsigned u; half2v h; } z; z.h = pkh(a, b); return z.u;
}
__device__ __forceinline__ half2v ldw(const unsigned* p, int i) {
    union { unsigned u; half2v h; } z; z.u = p[i]; return z.h;
}

// ---- ws layout ----
// u32 region (f16x2 pairs):
#define U_PJRZ 0    // [8][6] j rz rows: L01 L23 R01 R23 H01 H23, * -log2e
#define U_PJNLR 48  // [4][4] j inn rows: L01 L23 R01 R23, * 2log2e
#define U_PJNH 64   // [4][2] j hn rows: H01 H23, * 2log2e
#define U_PMRZ 72   // [8][4] m rz rows: I01 I23 H01 H23, * -log2e
#define U_PMNI 104  // [4][2] m inn rows: I01 I23, * 2log2e
#define U_PMNH 112  // [4][2] m hn rows: H01 H23, * 2log2e
// f32 region (indices in floats):
#define F_BRZJ 120  // [8] (bih_j+bhh_j)[0:8] * -log2e
#define F_BINJ 128  // [4] bih_j[8:12] * 2log2e
#define F_BHNJ 132  // [4] bhh_j[8:12] * 2log2e
#define F_BRZM 136  // [8]
#define F_BINM 144  // [4]
#define F_BHNM 148  // [4]
#define F_WJ   152  // [4][2]
#define F_BJ   160  // [4]
#define F_WM   164  // [4][4]
#define F_BM   180  // [4]
#define F_WA   184  // [4]
#define F_BA   188  // [1]
#define W_TOT2 189

__global__ void pack_weights2(
    const float* __restrict__ Wj,    const float* __restrict__ bj,
    const float* __restrict__ Wm,    const float* __restrict__ bm,
    const float* __restrict__ Wih_j, const float* __restrict__ Whh_j,
    const float* __restrict__ bih_j, const float* __restrict__ bhh_j,
    const float* __restrict__ Wih_m, const float* __restrict__ Whh_m,
    const float* __restrict__ bih_m, const float* __restrict__ bhh_m,
    const float* __restrict__ Wa,    const float* __restrict__ ba,
    void* __restrict__ wsv)
{
    unsigned* wu = (unsigned*)wsv;
    float*    wf = (float*)wsv;
    int t = threadIdx.x;
    const float SN = -1.44269504088896f;   // sigmoid scale: exp2(SN*x)=e^-x
    const float ST =  2.88539008177793f;   // tanh scale:    exp2(ST*x)=e^(2x)
    if (t < 48) {                                    // j rz pairs
        int g = t / 6, p = t % 6; float a, b;
        if (p < 4) { a = Wih_j[g*8 + 2*p];     b = Wih_j[g*8 + 2*p + 1]; }
        else       { a = Whh_j[g*4 + 2*(p-4)]; b = Whh_j[g*4 + 2*(p-4) + 1]; }
        wu[t] = pku(a * SN, b * SN);
    } else if (t < 64) {                             // j inn LR pairs
        int i = t - 48, u = i / 4, p = i % 4;
        wu[t] = pku(Wih_j[(8+u)*8 + 2*p] * ST, Wih_j[(8+u)*8 + 2*p + 1] * ST);
    } else if (t < 72) {                             // j hn H pairs
        int i = t - 64, u = i / 2, p = i % 2;
        wu[t] = pku(Whh_j[(8+u)*4 + 2*p] * ST, Whh_j[(8+u)*4 + 2*p + 1] * ST);
    } else if (t < 104) {                            // m rz pairs
        int i = t - 72, g = i / 4, p = i % 4; float a, b;
        if (p < 2) { a = Wih_m[g*4 + 2*p];     b = Wih_m[g*4 + 2*p + 1]; }
        else       { a = Whh_m[g*4 + 2*(p-2)]; b = Whh_m[g*4 + 2*(p-2) + 1]; }
        wu[t] = pku(a * SN, b * SN);
    } else if (t < 112) {                            // m inn pairs
        int i = t - 104, u = i / 2, p = i % 2;
        wu[t] = pku(Wih_m[(8+u)*4 + 2*p] * ST, Wih_m[(8+u)*4 + 2*p + 1] * ST);
    } else if (t < 120) {                            // m hn pairs
        int i = t - 112, u = i / 2, p = i % 2;
        wu[t] = pku(Whh_m[(8+u)*4 + 2*p] * ST, Whh_m[(8+u)*4 + 2*p + 1] * ST);
    } else if (t < 128) { wf[t] = (bih_j[t-120] + bhh_j[t-120]) * SN; }
    else if (t < 132)   { wf[t] = bih_j[8 + t - 128] * ST; }
    else if (t < 136)   { wf[t] = bhh_j[8 + t - 132] * ST; }
    else if (t < 144)   { wf[t] = (bih_m[t-136] + bhh_m[t-136]) * SN; }
    else if (t < 148)   { wf[t] = bih_m[8 + t - 144] * ST; }
    else if (t < 152)   { wf[t] = bhh_m[8 + t - 148] * ST; }
    else if (t < 160)   { wf[t] = Wj[t - 152]; }
    else if (t < 164)   { wf[t] = bj[t - 160]; }
    else if (t < 180)   { wf[t] = Wm[t - 164]; }
    else if (t < 184)   { wf[t] = bm[t - 180]; }
    else if (t < 188)   { wf[t] = Wa[t - 184]; }
    else if (t == 188)  { wf[t] = ba[0]; }
}

__global__ __launch_bounds__(256)
__attribute__((amdgpu_waves_per_eu(4, 4)))
void aggreg_policy_dot2(
    const float* __restrict__ x, const void* __restrict__ wsv,
    float* __restrict__ out, int nrows)
{
    const unsigned* WU = (const unsigned*)wsv;
    const float*    WF = (const float*)wsv;
    int b = blockIdx.x * blockDim.x + threadIdx.x;
    if (b >= nrows) return;

    const float2* xr2 = (const float2*)(x + (long)b * 18);
    float xin[18];
    #pragma unroll
    for (int i = 0; i < 9; ++i) { float2 v = xr2[i]; xin[2*i] = v.x; xin[2*i+1] = v.y; }

    // single-copy state, updated in place each iteration
    float hj[7][4], hm[4];
    half2v pj[7][2], pm[2];

    #pragma unroll
    for (int k = 0; k < 7; ++k) {
        #pragma unroll
        for (int u = 0; u < 4; ++u)
            hj[k][u] = fmaf(WF[F_WJ + u*2], xin[4 + k],
                       fmaf(WF[F_WJ + u*2 + 1], xin[11 + k], WF[F_BJ + u]));
        pj[k][0] = pkh(hj[k][0], hj[k][1]);
        pj[k][1] = pkh(hj[k][2], hj[k][3]);
    }
    #pragma unroll
    for (int u = 0; u < 4; ++u) {
        float a = WF[F_BM + u];
        #pragma unroll
        for (int v = 0; v < 4; ++v) a = fmaf(WF[F_WM + u*4 + v], xin[v], a);
        hm[u] = a;
    }
    pm[0] = pkh(hm[0], hm[1]);
    pm[1] = pkh(hm[2], hm[3]);

    #pragma unroll 1   // one copy of the body in I$; trip count 7
    for (int it = 0; it < 7; ++it) {
        // ---- m-GRU: input = OLD hj[0], hidden = OLD hm; commit at end ----
        float hmn[4]; half2v pmn[2];
        {
            float pre[8], inn[4], hn[4];
            #pragma unroll
            for (int g = 0; g < 8; ++g) {
                float a = WF[F_BRZM + g];
                a = fdot2(pj[0][0], ldw(WU, U_PMRZ + g*4 + 0), a);
                a = fdot2(pj[0][1], ldw(WU, U_PMRZ + g*4 + 1), a);
                a = fdot2(pm[0],    ldw(WU, U_PMRZ + g*4 + 2), a);
                a = fdot2(pm[1],    ldw(WU, U_PMRZ + g*4 + 3), a);
                pre[g] = a;
            }
            #pragma unroll
            for (int u = 0; u < 4; ++u) {
                float a = WF[F_BINM + u];
                a = fdot2(pj[0][0], ldw(WU, U_PMNI + u*2 + 0), a);
                a = fdot2(pj[0][1], ldw(WU, U_PMNI + u*2 + 1), a);
                inn[u] = a;
                float c = WF[F_BHNM + u];
                c = fdot2(pm[0], ldw(WU, U_PMNH + u*2 + 0), c);
                c = fdot2(pm[1], ldw(WU, U_PMNH + u*2 + 1), c);
                hn[u] = c;
            }
            #pragma unroll
            for (int u = 0; u < 4; ++u) {
                float r = frcp(1.0f + fexp2(pre[u]));
                float z = frcp(1.0f + fexp2(pre[4 + u]));
                float narg = fmaf(r, hn[u], inn[u]);
                float n = fmaf(-2.0f, frcp(1.0f + fexp2(narg)), 1.0f);
                hmn[u] = fmaf(z, hm[u] - n, n);
            }
            pmn[0] = pkh(hmn[0], hmn[1]);
            pmn[1] = pkh(hmn[2], hmn[3]);
        }

        // ---- j-GRU, left to right, in place.
        // cell k reads: op (OLD hj[k-1]) or OLD hm; pj[k] (not yet replaced);
        // pj[k+1] (not yet reached) -- all OLD values, matching the reference.
        float op[4]; half2v opp[2];
        #pragma unroll
        for (int k = 0; k < 7; ++k) {
            half2v L0 = (k == 0) ? pm[0] : opp[0];
            half2v L1 = (k == 0) ? pm[1] : opp[1];
            half2v H0 = pj[k][0], H1 = pj[k][1];
            float pre[8], inn[4], hn[4];
            #pragma unroll
            for (int g = 0; g < 8; ++g) {
                float a = WF[F_BRZJ + g];
                a = fdot2(L0, ldw(WU, U_PJRZ + g*6 + 0), a);
                a = fdot2(L1, ldw(WU, U_PJRZ + g*6 + 1), a);
                if (k != 6) {   // right neighbor of last cell is zero-pad
                    a = fdot2(pj[k+1][0], ldw(WU, U_PJRZ + g*6 + 2), a);
                    a = fdot2(pj[k+1][1], ldw(WU, U_PJRZ + g*6 + 3), a);
                }
                a = fdot2(H0, ldw(WU, U_PJRZ + g*6 + 4), a);
                a = fdot2(H1, ldw(WU, U_PJRZ + g*6 + 5), a);
                pre[g] = a;
            }
            #pragma unroll
            for (int u = 0; u < 4; ++u) {
                float a = WF[F_BINJ + u];
                a = fdot2(L0, ldw(WU, U_PJNLR + u*4 + 0), a);
                a = fdot2(L1, ldw(WU, U_PJNLR + u*4 + 1), a);
                if (k != 6) {
                    a = fdot2(pj[k+1][0], ldw(WU, U_PJNLR + u*4 + 2), a);
                    a = fdot2(pj[k+1][1], ldw(WU, U_PJNLR + u*4 + 3), a);
                }
                inn[u] = a;
                float c = WF[F_BHNJ + u];
                c = fdot2(H0, ldw(WU, U_PJNH + u*2 + 0), c);
                c = fdot2(H1, ldw(WU, U_PJNH + u*2 + 1), c);
                hn[u] = c;
            }
            float nh[4];
            #pragma unroll
            for (int u = 0; u < 4; ++u) {
                float r = frcp(1.0f + fexp2(pre[u]));
                float z = frcp(1.0f + fexp2(pre[4 + u]));
                float narg = fmaf(r, hn[u], inn[u]);
                float n = fmaf(-2.0f, frcp(1.0f + fexp2(narg)), 1.0f);
                nh[u] = fmaf(z, hj[k][u] - n, n);
            }
            // save OLD cell k into op/opp, then commit new value in place
            #pragma unroll
            for (int u = 0; u < 4; ++u) { op[u] = hj[k][u]; hj[k][u] = nh[u]; }
            opp[0] = pj[k][0]; opp[1] = pj[k][1];
            pj[k][0] = pkh(nh[0], nh[1]);
            pj[k][1] = pkh(nh[2], nh[3]);
        }

        #pragma unroll
        for (int u = 0; u < 4; ++u) hm[u] = hmn[u];
        pm[0] = pmn[0]; pm[1] = pmn[1];
    }

    float* orow = out + (long)b * 7;
    #pragma unroll
    for (int k = 0; k < 7; ++k) {
        float a = WF[F_BA];
        #pragma unroll
        for (int u = 0; u < 4; ++u) a = fmaf(WF[F_WA + u], hj[k][u], a);
        orow[k] = a;
    }
}

// ---------------- f32 fallback (only if ws too small; never expected) --------
__device__ __forceinline__ float sigmoid_f(float x) {
    return frcp(1.0f + fexp2(-1.44269504088896f * x));
}
__device__ __forceinline__ float tanh_f(float x) {
    float e = fexp2(2.88539008177793f * x);
    return 1.0f - 2.0f * frcp(1.0f + e);
}

__global__ __launch_bounds__(256) void aggreg_policy_fallback(
    const float* __restrict__ x,
    const float* __restrict__ Wj,    const float* __restrict__ bj,
    const float* __restrict__ Wm,    const float* __restrict__ bm,
    const float* __restrict__ Wih_j, const float* __restrict__ Whh_j,
    const float* __restrict__ bih_j, const float* __restrict__ bhh_j,
    const float* __restrict__ Wih_m, const float* __restrict__ Whh_m,
    const float* __restrict__ bih_m, const float* __restrict__ bhh_m,
    const float* __restrict__ Wa,    const float* __restrict__ ba,
    float* __restrict__ out, int nrows)
{
    int b = blockIdx.x * blockDim.x + threadIdx.x;
    if (b >= nrows) return;
    const float* xr = x + (long)b * 18;
    float obs[4], jv[7], jd[7];
    #pragma unroll
    for (int i = 0; i < 4; ++i) obs[i] = xr[i];
    #pragma unroll
    for (int i = 0; i < 7; ++i) jv[i] = xr[4 + i];
    #pragma unroll
    for (int i = 0; i < 7; ++i) jd[i] = xr[11 + i];
    float hj[7][4], hm[4];
    #pragma unroll
    for (int k = 0; k < 7; ++k)
        #pragma unroll
        for (int u = 0; u < 4; ++u)
            hj[k][u] = fmaf(Wj[u*2], jv[k], fmaf(Wj[u*2+1], jd[k], bj[u]));
    #pragma unroll
    for (int u = 0; u < 4; ++u) {
        float a = bm[u];
        #pragma unroll
        for (int v = 0; v < 4; ++v) a = fmaf(Wm[u*4+v], obs[v], a);
        hm[u] = a;
    }
    float bmrz[8], bjrz[8];
    #pragma unroll
    for (int g = 0; g < 8; ++g) { bmrz[g] = bih_m[g]+bhh_m[g]; bjrz[g] = bih_j[g]+bhh_j[g]; }
    #pragma unroll 1
    for (int it = 0; it < 7; ++it) {
        float hmn[4];
        {
            float pre[8], inn[4], hn[4];
            #pragma unroll
            for (int g = 0; g < 8; ++g) {
                float a = bmrz[g];
                #pragma unroll
                for (int v = 0; v < 4; ++v) a = fmaf(Wih_m[g*4+v], hj[0][v], a);
                #pragma unroll
                for (int v = 0; v < 4; ++v) a = fmaf(Whh_m[g*4+v], hm[v], a);
                pre[g] = a;
            }
            #pragma unroll
            for (int u = 0; u < 4; ++u) {
                float a = bih_m[8+u];
                #pragma unroll
                for (int v = 0; v < 4; ++v) a = fmaf(Wih_m[(8+u)*4+v], hj[0][v], a);
                inn[u] = a;
                float c = bhh_m[8+u];
                #pragma unroll
                for (int v = 0; v < 4; ++v) c = fmaf(Whh_m[(8+u)*4+v], hm[v], c);
                hn[u] = c;
            }
            #pragma unroll
            for (int u = 0; u < 4; ++u) {
                float r = sigmoid_f(pre[u]);
                float z = sigmoid_f(pre[4+u]);
                float n = tanh_f(fmaf(r, hn[u], inn[u]));
                hmn[u] = fmaf(z, hm[u]-n, n);
            }
        }
        float nh[7][4];
        #pragma unroll
        for (int k = 0; k < 7; ++k) {
            float L[4], R[4];
            #pragma unroll
            for (int u = 0; u < 4; ++u) {
                L[u] = (k == 0) ? hm[u] : hj[k-1][u];
                R[u] = (k == 6) ? 0.0f  : hj[k+1][u];
            }
            float pre[8], inn[4], hn[4];
            #pragma unroll
            for (int g = 0; g < 8; ++g) {
                float a = bjrz[g];
                #pragma unroll
                for (int v = 0; v < 4; ++v) a = fmaf(Wih_j[g*8+v], L[v], a);
                #pragma unroll
                for (int v = 0; v < 4; ++v) a = fmaf(Wih_j[g*8+4+v], R[v], a);
                #pragma unroll
                for (int v = 0; v < 4; ++v) a = fmaf(Whh_j[g*4+v], hj[k][v], a);
                pre[g] = a;
            }
            #pragma unroll
            for (int u = 0; u < 4; ++u) {
                float a = bih_j[8+u];
                #pragma unroll
                for (int v = 0; v < 4; ++v) a = fmaf(Wih_j[(8+u)*8+v], L[v], a);
                #pragma unroll
                for (int v = 0; v < 4; ++v) a = fmaf(Wih_j[(8+u)*8+4+v], R[v], a);
                inn[u] = a;
                float c = bhh_j[8+u];
                #pragma unroll
                for (int v = 0; v < 4; ++v) c = fmaf(Whh_j[(8+u)*4+v], hj[k][v], c);
                hn[u] = c;
            }
            #pragma unroll
            for (int u = 0; u < 4; ++u) {
                float r = sigmoid_f(pre[u]);
                float z = sigmoid_f(pre[4+u]);
                float n = tanh_f(fmaf(r, hn[u], inn[u]));
                nh[k][u] = fmaf(z, hj[k][u]-n, n);
            }
        }
        #pragma unroll
        for (int k = 0; k < 7; ++k)
            #pragma unroll
            for (int u = 0; u < 4; ++u) hj[k][u] = nh[k][u];
        #pragma unroll
        for (int u = 0; u < 4; ++u) hm[u] = hmn[u];
    }
    float* orow = out + (long)b * 7;
    #pragma unroll
    for (int k = 0; k < 7; ++k) {
        float a = ba[0];
        #pragma unroll
        for (int u = 0; u < 4; ++u) a = fmaf(Wa[u], hj[k][u], a);
        orow[k] = a;
    }
}

extern "C" void kernel_launch(void* const* d_in, const int* in_sizes, int n_in,
                              void* d_out, int out_size, void* d_ws, size_t ws_size,
                              hipStream_t stream) {
    const float* x     = (const float*)d_in[0];
    const float* Wj    = (const float*)d_in[1];
    const float* bj    = (const float*)d_in[2];
    const float* Wm    = (const float*)d_in[3];
    const float* bm    = (const float*)d_in[4];
    const float* Wih_j = (const float*)d_in[5];
    const float* Whh_j = (const float*)d_in[6];
    const float* bih_j = (const float*)d_in[7];
    const float* bhh_j = (const float*)d_in[8];
    const float* Wih_m = (const float*)d_in[9];
    const float* Whh_m = (const float*)d_in[10];
    const float* bih_m = (const float*)d_in[11];
    const float* bhh_m = (const float*)d_in[12];
    const float* Wa    = (const float*)d_in[13];
    const float* ba    = (const float*)d_in[14];
    float* out = (float*)d_out;

    int nrows = in_sizes[0] / 18;
    int block = 256;
    int grid = (nrows + block - 1) / block;

    if (ws_size >= W_TOT2 * sizeof(float)) {
        pack_weights2<<<1, 256, 0, stream>>>(
            Wj, bj, Wm, bm, Wih_j, Whh_j, bih_j, bhh_j,
            Wih_m, Whh_m, bih_m, bhh_m, Wa, ba, d_ws);
        aggreg_policy_dot2<<<grid, block, 0, stream>>>(x, d_ws, out, nrows);
    } else {
        aggreg_policy_fallback<<<grid, block, 0, stream>>>(
            x, Wj, bj, Wm, bm, Wih_j, Whh_j, bih_j, bhh_j,
            Wih_m, Whh_m, bih_m, bhh_m, Wa, ba, out, nrows);
    }
}

// Round 5
// 137.441 us; speedup vs baseline: 1.0389x; 1.0389x over previous
//
#include <hip/hip_runtime.h>

// One thread = one row. Matmuls via v_dot2_f32_f16 (2 f16 MACs/instr, f32
// accum), weights pre-packed+activation-scaled into d_ws as f16x2. State
// updated IN PLACE (left-to-right, old-prev carried in registers).
// GRU epilogue uses the fused form  h' = (en*(ez+h) + (h-ez)) / ((en+1)(ez+1))
// with ez=e^-zpre, en=e^(2*narg): 3 exp2 + 2 rcp per unit (was 3+3).
// Plain __launch_bounds__(256): VGPR ~52 fits the 64-reg / 8-waves-per-EU
// boundary (round-4 waves_per_eu(4,4) capped occupancy at 37%).

typedef _Float16 half2v __attribute__((ext_vector_type(2)));

__device__ __forceinline__ float fexp2(float x) { return __builtin_amdgcn_exp2f(x); }
__device__ __forceinline__ float frcp(float x)  { return __builtin_amdgcn_rcpf(x); }
__device__ __forceinline__ float fdot2(half2v a, half2v b, float c) {
    return __builtin_amdgcn_fdot2(a, b, c, false);
}
__device__ __forceinline__ half2v pkh(float a, float b) {
    return half2v{(_Float16)a, (_Float16)b};
}
__device__ __forceinline__ unsigned pku(float a, float b) {
    union { unsigned u; half2v h; } z; z.h = pkh(a, b); return z.u;
}
__device__ __forceinline__ half2v ldw(const unsigned* p, int i) {
    union { unsigned u; half2v h; } z; z.u = p[i]; return z.h;
}

// GRU epilogue, fused:  pre_r, pre_z scaled by -log2e; inn, hn scaled by 2log2e.
// r = 1/(1+e^-rpre); narg = inn + r*hn; en = e^(2x); ez = e^-zpre;
// h' = (en*(ez+h) + (h-ez)) * rcp((en+1)*(ez+1))
__device__ __forceinline__ float gru_out(float pre_r, float pre_z,
                                         float inn, float hn, float h) {
    float er = fexp2(pre_r);
    float r  = frcp(1.0f + er);
    float ez = fexp2(pre_z);
    float narg = fmaf(r, hn, inn);
    float en = fexp2(narg);
    float t1 = ez + h;
    float t2 = h - ez;
    float num = fmaf(en, t1, t2);
    float s   = ez + 1.0f;
    float den = fmaf(en, s, s);      // (en+1)*(ez+1)
    return num * frcp(den);
}

// ---- ws layout ----
// u32 region (f16x2 pairs):
#define U_PJRZ 0    // [8][6] j rz rows: L01 L23 R01 R23 H01 H23, * -log2e
#define U_PJNLR 48  // [4][4] j inn rows: L01 L23 R01 R23, * 2log2e
#define U_PJNH 64   // [4][2] j hn rows: H01 H23, * 2log2e
#define U_PMRZ 72   // [8][4] m rz rows: I01 I23 H01 H23, * -log2e
#define U_PMNI 104  // [4][2] m inn rows: I01 I23, * 2log2e
#define U_PMNH 112  // [4][2] m hn rows: H01 H23, * 2log2e
// f32 region (indices in floats):
#define F_BRZJ 120  // [8] (bih_j+bhh_j)[0:8] * -log2e
#define F_BINJ 128  // [4] bih_j[8:12] * 2log2e
#define F_BHNJ 132  // [4] bhh_j[8:12] * 2log2e
#define F_BRZM 136  // [8]
#define F_BINM 144  // [4]
#define F_BHNM 148  // [4]
#define F_WJ   152  // [4][2]
#define F_BJ   160  // [4]
#define F_WM   164  // [4][4]
#define F_BM   180  // [4]
#define F_WA   184  // [4]
#define F_BA   188  // [1]
#define W_TOT2 189

__global__ void pack_weights2(
    const float* __restrict__ Wj,    const float* __restrict__ bj,
    const float* __restrict__ Wm,    const float* __restrict__ bm,
    const float* __restrict__ Wih_j, const float* __restrict__ Whh_j,
    const float* __restrict__ bih_j, const float* __restrict__ bhh_j,
    const float* __restrict__ Wih_m, const float* __restrict__ Whh_m,
    const float* __restrict__ bih_m, const float* __restrict__ bhh_m,
    const float* __restrict__ Wa,    const float* __restrict__ ba,
    void* __restrict__ wsv)
{
    unsigned* wu = (unsigned*)wsv;
    float*    wf = (float*)wsv;
    int t = threadIdx.x;
    const float SN = -1.44269504088896f;   // sigmoid scale: exp2(SN*x)=e^-x
    const float ST =  2.88539008177793f;   // tanh scale:    exp2(ST*x)=e^(2x)
    if (t < 48) {                                    // j rz pairs
        int g = t / 6, p = t % 6; float a, b;
        if (p < 4) { a = Wih_j[g*8 + 2*p];     b = Wih_j[g*8 + 2*p + 1]; }
        else       { a = Whh_j[g*4 + 2*(p-4)]; b = Whh_j[g*4 + 2*(p-4) + 1]; }
        wu[t] = pku(a * SN, b * SN);
    } else if (t < 64) {                             // j inn LR pairs
        int i = t - 48, u = i / 4, p = i % 4;
        wu[t] = pku(Wih_j[(8+u)*8 + 2*p] * ST, Wih_j[(8+u)*8 + 2*p + 1] * ST);
    } else if (t < 72) {                             // j hn H pairs
        int i = t - 64, u = i / 2, p = i % 2;
        wu[t] = pku(Whh_j[(8+u)*4 + 2*p] * ST, Whh_j[(8+u)*4 + 2*p + 1] * ST);
    } else if (t < 104) {                            // m rz pairs
        int i = t - 72, g = i / 4, p = i % 4; float a, b;
        if (p < 2) { a = Wih_m[g*4 + 2*p];     b = Wih_m[g*4 + 2*p + 1]; }
        else       { a = Whh_m[g*4 + 2*(p-2)]; b = Whh_m[g*4 + 2*(p-2) + 1]; }
        wu[t] = pku(a * SN, b * SN);
    } else if (t < 112) {                            // m inn pairs
        int i = t - 104, u = i / 2, p = i % 2;
        wu[t] = pku(Wih_m[(8+u)*4 + 2*p] * ST, Wih_m[(8+u)*4 + 2*p + 1] * ST);
    } else if (t < 120) {                            // m hn pairs
        int i = t - 112, u = i / 2, p = i % 2;
        wu[t] = pku(Whh_m[(8+u)*4 + 2*p] * ST, Whh_m[(8+u)*4 + 2*p + 1] * ST);
    } else if (t < 128) { wf[t] = (bih_j[t-120] + bhh_j[t-120]) * SN; }
    else if (t < 132)   { wf[t] = bih_j[8 + t - 128] * ST; }
    else if (t < 136)   { wf[t] = bhh_j[8 + t - 132] * ST; }
    else if (t < 144)   { wf[t] = (bih_m[t-136] + bhh_m[t-136]) * SN; }
    else if (t < 148)   { wf[t] = bih_m[8 + t - 144] * ST; }
    else if (t < 152)   { wf[t] = bhh_m[8 + t - 148] * ST; }
    else if (t < 160)   { wf[t] = Wj[t - 152]; }
    else if (t < 164)   { wf[t] = bj[t - 160]; }
    else if (t < 180)   { wf[t] = Wm[t - 164]; }
    else if (t < 184)   { wf[t] = bm[t - 180]; }
    else if (t < 188)   { wf[t] = Wa[t - 184]; }
    else if (t == 188)  { wf[t] = ba[0]; }
}

__global__ __launch_bounds__(256)
void aggreg_policy_dot2(
    const float* __restrict__ x, const void* __restrict__ wsv,
    float* __restrict__ out, int nrows)
{
    const unsigned* WU = (const unsigned*)wsv;
    const float*    WF = (const float*)wsv;
    int b = blockIdx.x * blockDim.x + threadIdx.x;
    if (b >= nrows) return;

    const float2* xr2 = (const float2*)(x + (long)b * 18);
    float xin[18];
    #pragma unroll
    for (int i = 0; i < 9; ++i) { float2 v = xr2[i]; xin[2*i] = v.x; xin[2*i+1] = v.y; }

    // single-copy state, updated in place each iteration
    float hj[7][4], hm[4];
    half2v pj[7][2], pm[2];

    #pragma unroll
    for (int k = 0; k < 7; ++k) {
        #pragma unroll
        for (int u = 0; u < 4; ++u)
            hj[k][u] = fmaf(WF[F_WJ + u*2], xin[4 + k],
                       fmaf(WF[F_WJ + u*2 + 1], xin[11 + k], WF[F_BJ + u]));
        pj[k][0] = pkh(hj[k][0], hj[k][1]);
        pj[k][1] = pkh(hj[k][2], hj[k][3]);
    }
    #pragma unroll
    for (int u = 0; u < 4; ++u) {
        float a = WF[F_BM + u];
        #pragma unroll
        for (int v = 0; v < 4; ++v) a = fmaf(WF[F_WM + u*4 + v], xin[v], a);
        hm[u] = a;
    }
    pm[0] = pkh(hm[0], hm[1]);
    pm[1] = pkh(hm[2], hm[3]);

    #pragma unroll 1   // one copy of the body in I$; trip count 7
    for (int it = 0; it < 7; ++it) {
        // ---- m-GRU: input = OLD hj[0], hidden = OLD hm; commit at end ----
        float hmn[4]; half2v pmn[2];
        {
            float pre[8], inn[4], hn[4];
            #pragma unroll
            for (int g = 0; g < 8; ++g) {
                float a = WF[F_BRZM + g];
                a = fdot2(pj[0][0], ldw(WU, U_PMRZ + g*4 + 0), a);
                a = fdot2(pj[0][1], ldw(WU, U_PMRZ + g*4 + 1), a);
                a = fdot2(pm[0],    ldw(WU, U_PMRZ + g*4 + 2), a);
                a = fdot2(pm[1],    ldw(WU, U_PMRZ + g*4 + 3), a);
                pre[g] = a;
            }
            #pragma unroll
            for (int u = 0; u < 4; ++u) {
                float a = WF[F_BINM + u];
                a = fdot2(pj[0][0], ldw(WU, U_PMNI + u*2 + 0), a);
                a = fdot2(pj[0][1], ldw(WU, U_PMNI + u*2 + 1), a);
                inn[u] = a;
                float c = WF[F_BHNM + u];
                c = fdot2(pm[0], ldw(WU, U_PMNH + u*2 + 0), c);
                c = fdot2(pm[1], ldw(WU, U_PMNH + u*2 + 1), c);
                hn[u] = c;
            }
            #pragma unroll
            for (int u = 0; u < 4; ++u)
                hmn[u] = gru_out(pre[u], pre[4 + u], inn[u], hn[u], hm[u]);
            pmn[0] = pkh(hmn[0], hmn[1]);
            pmn[1] = pkh(hmn[2], hmn[3]);
        }

        // ---- j-GRU, left to right, in place.
        // cell k reads: opp (OLD pj[k-1]) or OLD pm; pj[k] (not yet replaced);
        // pj[k+1] (not yet reached) -- all OLD values, matching the reference.
        half2v opp[2];
        #pragma unroll
        for (int k = 0; k < 7; ++k) {
            half2v L0 = (k == 0) ? pm[0] : opp[0];
            half2v L1 = (k == 0) ? pm[1] : opp[1];
            half2v H0 = pj[k][0], H1 = pj[k][1];
            float pre[8], inn[4], hn[4];
            #pragma unroll
            for (int g = 0; g < 8; ++g) {
                float a = WF[F_BRZJ + g];
                a = fdot2(L0, ldw(WU, U_PJRZ + g*6 + 0), a);
                a = fdot2(L1, ldw(WU, U_PJRZ + g*6 + 1), a);
                if (k != 6) {   // right neighbor of last cell is zero-pad
                    a = fdot2(pj[k+1][0], ldw(WU, U_PJRZ + g*6 + 2), a);
                    a = fdot2(pj[k+1][1], ldw(WU, U_PJRZ + g*6 + 3), a);
                }
                a = fdot2(H0, ldw(WU, U_PJRZ + g*6 + 4), a);
                a = fdot2(H1, ldw(WU, U_PJRZ + g*6 + 5), a);
                pre[g] = a;
            }
            #pragma unroll
            for (int u = 0; u < 4; ++u) {
                float a = WF[F_BINJ + u];
                a = fdot2(L0, ldw(WU, U_PJNLR + u*4 + 0), a);
                a = fdot2(L1, ldw(WU, U_PJNLR + u*4 + 1), a);
                if (k != 6) {
                    a = fdot2(pj[k+1][0], ldw(WU, U_PJNLR + u*4 + 2), a);
                    a = fdot2(pj[k+1][1], ldw(WU, U_PJNLR + u*4 + 3), a);
                }
                inn[u] = a;
                float c = WF[F_BHNJ + u];
                c = fdot2(H0, ldw(WU, U_PJNH + u*2 + 0), c);
                c = fdot2(H1, ldw(WU, U_PJNH + u*2 + 1), c);
                hn[u] = c;
            }
            float nh[4];
            #pragma unroll
            for (int u = 0; u < 4; ++u)
                nh[u] = gru_out(pre[u], pre[4 + u], inn[u], hn[u], hj[k][u]);
            // commit: save OLD packed cell k, then overwrite in place
            opp[0] = pj[k][0]; opp[1] = pj[k][1];
            #pragma unroll
            for (int u = 0; u < 4; ++u) hj[k][u] = nh[u];
            pj[k][0] = pkh(nh[0], nh[1]);
            pj[k][1] = pkh(nh[2], nh[3]);
        }

        #pragma unroll
        for (int u = 0; u < 4; ++u) hm[u] = hmn[u];
        pm[0] = pmn[0]; pm[1] = pmn[1];
    }

    float* orow = out + (long)b * 7;
    #pragma unroll
    for (int k = 0; k < 7; ++k) {
        float a = WF[F_BA];
        #pragma unroll
        for (int u = 0; u < 4; ++u) a = fmaf(WF[F_WA + u], hj[k][u], a);
        orow[k] = a;
    }
}

// ---------------- f32 fallback (only if ws too small; never expected) --------
__device__ __forceinline__ float sigmoid_f(float x) {
    return frcp(1.0f + fexp2(-1.44269504088896f * x));
}
__device__ __forceinline__ float tanh_f(float x) {
    float e = fexp2(2.88539008177793f * x);
    return 1.0f - 2.0f * frcp(1.0f + e);
}

__global__ __launch_bounds__(256) void aggreg_policy_fallback(
    const float* __restrict__ x,
    const float* __restrict__ Wj,    const float* __restrict__ bj,
    const float* __restrict__ Wm,    const float* __restrict__ bm,
    const float* __restrict__ Wih_j, const float* __restrict__ Whh_j,
    const float* __restrict__ bih_j, const float* __restrict__ bhh_j,
    const float* __restrict__ Wih_m, const float* __restrict__ Whh_m,
    const float* __restrict__ bih_m, const float* __restrict__ bhh_m,
    const float* __restrict__ Wa,    const float* __restrict__ ba,
    float* __restrict__ out, int nrows)
{
    int b = blockIdx.x * blockDim.x + threadIdx.x;
    if (b >= nrows) return;
    const float* xr = x + (long)b * 18;
    float obs[4], jv[7], jd[7];
    #pragma unroll
    for (int i = 0; i < 4; ++i) obs[i] = xr[i];
    #pragma unroll
    for (int i = 0; i < 7; ++i) jv[i] = xr[4 + i];
    #pragma unroll
    for (int i = 0; i < 7; ++i) jd[i] = xr[11 + i];
    float hj[7][4], hm[4];
    #pragma unroll
    for (int k = 0; k < 7; ++k)
        #pragma unroll
        for (int u = 0; u < 4; ++u)
            hj[k][u] = fmaf(Wj[u*2], jv[k], fmaf(Wj[u*2+1], jd[k], bj[u]));
    #pragma unroll
    for (int u = 0; u < 4; ++u) {
        float a = bm[u];
        #pragma unroll
        for (int v = 0; v < 4; ++v) a = fmaf(Wm[u*4+v], obs[v], a);
        hm[u] = a;
    }
    float bmrz[8], bjrz[8];
    #pragma unroll
    for (int g = 0; g < 8; ++g) { bmrz[g] = bih_m[g]+bhh_m[g]; bjrz[g] = bih_j[g]+bhh_j[g]; }
    #pragma unroll 1
    for (int it = 0; it < 7; ++it) {
        float hmn[4];
        {
            float pre[8], inn[4], hn[4];
            #pragma unroll
            for (int g = 0; g < 8; ++g) {
                float a = bmrz[g];
                #pragma unroll
                for (int v = 0; v < 4; ++v) a = fmaf(Wih_m[g*4+v], hj[0][v], a);
                #pragma unroll
                for (int v = 0; v < 4; ++v) a = fmaf(Whh_m[g*4+v], hm[v], a);
                pre[g] = a;
            }
            #pragma unroll
            for (int u = 0; u < 4; ++u) {
                float a = bih_m[8+u];
                #pragma unroll
                for (int v = 0; v < 4; ++v) a = fmaf(Wih_m[(8+u)*4+v], hj[0][v], a);
                inn[u] = a;
                float c = bhh_m[8+u];
                #pragma unroll
                for (int v = 0; v < 4; ++v) c = fmaf(Whh_m[(8+u)*4+v], hm[v], c);
                hn[u] = c;
            }
            #pragma unroll
            for (int u = 0; u < 4; ++u) {
                float r = sigmoid_f(pre[u]);
                float z = sigmoid_f(pre[4+u]);
                float n = tanh_f(fmaf(r, hn[u], inn[u]));
                hmn[u] = fmaf(z, hm[u]-n, n);
            }
        }
        float nh[7][4];
        #pragma unroll
        for (int k = 0; k < 7; ++k) {
            float L[4], R[4];
            #pragma unroll
            for (int u = 0; u < 4; ++u) {
                L[u] = (k == 0) ? hm[u] : hj[k-1][u];
                R[u] = (k == 6) ? 0.0f  : hj[k+1][u];
            }
            float pre[8], inn[4], hn[4];
            #pragma unroll
            for (int g = 0; g < 8; ++g) {
                float a = bjrz[g];
                #pragma unroll
                for (int v = 0; v < 4; ++v) a = fmaf(Wih_j[g*8+v], L[v], a);
                #pragma unroll
                for (int v = 0; v < 4; ++v) a = fmaf(Wih_j[g*8+4+v], R[v], a);
                #pragma unroll
                for (int v = 0; v < 4; ++v) a = fmaf(Whh_j[g*4+v], hj[k][v], a);
                pre[g] = a;
            }
            #pragma unroll
            for (int u = 0; u < 4; ++u) {
                float a = bih_j[8+u];
                #pragma unroll
                for (int v = 0; v < 4; ++v) a = fmaf(Wih_j[(8+u)*8+v], L[v], a);
                #pragma unroll
                for (int v = 0; v < 4; ++v) a = fmaf(Wih_j[(8+u)*8+4+v], R[v], a);
                inn[u] = a;
                float c = bhh_j[8+u];
                #pragma unroll
                for (int v = 0; v < 4; ++v) c = fmaf(Whh_j[(8+u)*4+v], hj[k][v], c);
                hn[u] = c;
            }
            #pragma unroll
            for (int u = 0; u < 4; ++u) {
                float r = sigmoid_f(pre[u]);
                float z = sigmoid_f(pre[4+u]);
                float n = tanh_f(fmaf(r, hn[u], inn[u]));
                nh[k][u] = fmaf(z, hj[k][u]-n, n);
            }
        }
        #pragma unroll
        for (int k = 0; k < 7; ++k)
            #pragma unroll
            for (int u = 0; u < 4; ++u) hj[k][u] = nh[k][u];
        #pragma unroll
        for (int u = 0; u < 4; ++u) hm[u] = hmn[u];
    }
    float* orow = out + (long)b * 7;
    #pragma unroll
    for (int k = 0; k < 7; ++k) {
        float a = ba[0];
        #pragma unroll
        for (int u = 0; u < 4; ++u) a = fmaf(Wa[u], hj[k][u], a);
        orow[k] = a;
    }
}

extern "C" void kernel_launch(void* const* d_in, const int* in_sizes, int n_in,
                              void* d_out, int out_size, void* d_ws, size_t ws_size,
                              hipStream_t stream) {
    const float* x     = (const float*)d_in[0];
    const float* Wj    = (const float*)d_in[1];
    const float* bj    = (const float*)d_in[2];
    const float* Wm    = (const float*)d_in[3];
    const float* bm    = (const float*)d_in[4];
    const float* Wih_j = (const float*)d_in[5];
    const float* Whh_j = (const float*)d_in[6];
    const float* bih_j = (const float*)d_in[7];
    const float* bhh_j = (const float*)d_in[8];
    const float* Wih_m = (const float*)d_in[9];
    const float* Whh_m = (const float*)d_in[10];
    const float* bih_m = (const float*)d_in[11];
    const float* bhh_m = (const float*)d_in[12];
    const float* Wa    = (const float*)d_in[13];
    const float* ba    = (const float*)d_in[14];
    float* out = (float*)d_out;

    int nrows = in_sizes[0] / 18;
    int block = 256;
    int grid = (nrows + block - 1) / block;

    if (ws_size >= W_TOT2 * sizeof(float)) {
        pack_weights2<<<1, 256, 0, stream>>>(
            Wj, bj, Wm, bm, Wih_j, Whh_j, bih_j, bhh_j,
            Wih_m, Whh_m, bih_m, bhh_m, Wa, ba, d_ws);
        aggreg_policy_dot2<<<grid, block, 0, stream>>>(x, d_ws, out, nrows);
    } else {
        aggreg_policy_fallback<<<grid, block, 0, stream>>>(
            x, Wj, bj, Wm, bm, Wih_j, Whh_j, bih_j, bhh_j,
            Wih_m, Whh_m, bih_m, bhh_m, Wa, ba, out, nrows);
    }
}

// Round 7
// 136.970 us; speedup vs baseline: 1.0425x; 1.0034x over previous
//
#include <hip/hip_runtime.h>

// One thread = one row. Matmuls via v_dot2_f32_f16 (2 f16 MACs/instr, f32
// accum), weights pre-packed+activation-scaled into d_ws as f16x2. State
// updated IN PLACE. GRU epilogue fused:
//   h' = (en*(ez+h) + (h-ez)) / ((en+1)(ez+1)),  en=e^(2*narg), ez=e^-zpre
// and ALL reciprocals batched 4-wide across the cell's 4 units:
//   one v_rcp of the product + 9 muls recovers four reciprocals
//   (4-unit group: 4 rcp -> 1 rcp + 9 mul; applied to r-gates and outputs).
// Trans ops/row: 672 exp2 + 112 rcp (was 672+448).

typedef _Float16 half2v __attribute__((ext_vector_type(2)));

__device__ __forceinline__ float fexp2(float x) { return __builtin_amdgcn_exp2f(x); }
__device__ __forceinline__ float frcp(float x)  { return __builtin_amdgcn_rcpf(x); }
__device__ __forceinline__ float fdot2(half2v a, half2v b, float c) {
    return __builtin_amdgcn_fdot2(a, b, c, false);
}
// v_cvt_pkrtz_f16_f32: single instruction f32x2 -> f16x2 (round-toward-zero).
// Builtin returns __fp16x2; bit-cast to our _Float16-based half2v.
__device__ __forceinline__ half2v pkh(float a, float b) {
    union { __fp16 __attribute__((ext_vector_type(2))) i; half2v o; } z;
    z.i = __builtin_amdgcn_cvt_pkrtz(a, b);
    return z.o;
}
__device__ __forceinline__ unsigned pku(float a, float b) {
    union { unsigned u; half2v h; } z; z.h = half2v{(_Float16)a, (_Float16)b}; return z.u;
}
__device__ __forceinline__ half2v ldw(const unsigned* p, int i) {
    union { unsigned u; half2v h; } z; z.u = p[i]; return z.h;
}

// Batched 4-way reciprocal: out[i] = 1/a[i], one v_rcp + 9 v_mul.
__device__ __forceinline__ void rcp4(const float a[4], float o[4]) {
    float p01 = a[0] * a[1];
    float p23 = a[2] * a[3];
    float rP  = frcp(p01 * p23);
    float q01 = rP * p23;          // 1/(a0*a1)
    float q23 = rP * p01;          // 1/(a2*a3)
    o[0] = a[1] * q01;
    o[1] = a[0] * q01;
    o[2] = a[3] * q23;
    o[3] = a[2] * q23;
}

// 4 GRU units at once. pre[0:4]=r-pre, pre[4:8]=z-pre (both *-log2e);
// inn,hn * 2log2e; h = old hidden. nh = new hidden.
__device__ __forceinline__ void gru_out4(const float pre[8], const float inn[4],
                                         const float hn[4], const float h[4],
                                         float nh[4]) {
    float ar[4], r[4];
    #pragma unroll
    for (int u = 0; u < 4; ++u) ar[u] = 1.0f + fexp2(pre[u]);
    rcp4(ar, r);
    float ez[4], en[4], num[4], den[4], inv[4];
    #pragma unroll
    for (int u = 0; u < 4; ++u) {
        ez[u] = fexp2(pre[4 + u]);
        en[u] = fexp2(fmaf(r[u], hn[u], inn[u]));
        num[u] = fmaf(en[u], ez[u] + h[u], h[u] - ez[u]);
        float s = ez[u] + 1.0f;
        den[u] = fmaf(en[u], s, s);          // (en+1)(ez+1)
    }
    rcp4(den, inv);
    #pragma unroll
    for (int u = 0; u < 4; ++u) nh[u] = num[u] * inv[u];
}

// ---- ws layout ----
// u32 region (f16x2 pairs):
#define U_PJRZ 0    // [8][6] j rz rows: L01 L23 R01 R23 H01 H23, * -log2e
#define U_PJNLR 48  // [4][4] j inn rows: L01 L23 R01 R23, * 2log2e
#define U_PJNH 64   // [4][2] j hn rows: H01 H23, * 2log2e
#define U_PMRZ 72   // [8][4] m rz rows: I01 I23 H01 H23, * -log2e
#define U_PMNI 104  // [4][2] m inn rows: I01 I23, * 2log2e
#define U_PMNH 112  // [4][2] m hn rows: H01 H23, * 2log2e
// f32 region (indices in floats):
#define F_BRZJ 120  // [8] (bih_j+bhh_j)[0:8] * -log2e
#define F_BINJ 128  // [4] bih_j[8:12] * 2log2e
#define F_BHNJ 132  // [4] bhh_j[8:12] * 2log2e
#define F_BRZM 136  // [8]
#define F_BINM 144  // [4]
#define F_BHNM 148  // [4]
#define F_WJ   152  // [4][2]
#define F_BJ   160  // [4]
#define F_WM   164  // [4][4]
#define F_BM   180  // [4]
#define F_WA   184  // [4]
#define F_BA   188  // [1]
#define W_TOT2 189

__global__ void pack_weights2(
    const float* __restrict__ Wj,    const float* __restrict__ bj,
    const float* __restrict__ Wm,    const float* __restrict__ bm,
    const float* __restrict__ Wih_j, const float* __restrict__ Whh_j,
    const float* __restrict__ bih_j, const float* __restrict__ bhh_j,
    const float* __restrict__ Wih_m, const float* __restrict__ Whh_m,
    const float* __restrict__ bih_m, const float* __restrict__ bhh_m,
    const float* __restrict__ Wa,    const float* __restrict__ ba,
    void* __restrict__ wsv)
{
    unsigned* wu = (unsigned*)wsv;
    float*    wf = (float*)wsv;
    int t = threadIdx.x;
    const float SN = -1.44269504088896f;   // sigmoid scale: exp2(SN*x)=e^-x
    const float ST =  2.88539008177793f;   // tanh scale:    exp2(ST*x)=e^(2x)
    if (t < 48) {                                    // j rz pairs
        int g = t / 6, p = t % 6; float a, b;
        if (p < 4) { a = Wih_j[g*8 + 2*p];     b = Wih_j[g*8 + 2*p + 1]; }
        else       { a = Whh_j[g*4 + 2*(p-4)]; b = Whh_j[g*4 + 2*(p-4) + 1]; }
        wu[t] = pku(a * SN, b * SN);
    } else if (t < 64) {                             // j inn LR pairs
        int i = t - 48, u = i / 4, p = i % 4;
        wu[t] = pku(Wih_j[(8+u)*8 + 2*p] * ST, Wih_j[(8+u)*8 + 2*p + 1] * ST);
    } else if (t < 72) {                             // j hn H pairs
        int i = t - 64, u = i / 2, p = i % 2;
        wu[t] = pku(Whh_j[(8+u)*4 + 2*p] * ST, Whh_j[(8+u)*4 + 2*p + 1] * ST);
    } else if (t < 104) {                            // m rz pairs
        int i = t - 72, g = i / 4, p = i % 4; float a, b;
        if (p < 2) { a = Wih_m[g*4 + 2*p];     b = Wih_m[g*4 + 2*p + 1]; }
        else       { a = Whh_m[g*4 + 2*(p-2)]; b = Whh_m[g*4 + 2*(p-2) + 1]; }
        wu[t] = pku(a * SN, b * SN);
    } else if (t < 112) {                            // m inn pairs
        int i = t - 104, u = i / 2, p = i % 2;
        wu[t] = pku(Wih_m[(8+u)*4 + 2*p] * ST, Wih_m[(8+u)*4 + 2*p + 1] * ST);
    } else if (t < 120) {                            // m hn pairs
        int i = t - 112, u = i / 2, p = i % 2;
        wu[t] = pku(Whh_m[(8+u)*4 + 2*p] * ST, Whh_m[(8+u)*4 + 2*p + 1] * ST);
    } else if (t < 128) { wf[t] = (bih_j[t-120] + bhh_j[t-120]) * SN; }
    else if (t < 132)   { wf[t] = bih_j[8 + t - 128] * ST; }
    else if (t < 136)   { wf[t] = bhh_j[8 + t - 132] * ST; }
    else if (t < 144)   { wf[t] = (bih_m[t-136] + bhh_m[t-136]) * SN; }
    else if (t < 148)   { wf[t] = bih_m[8 + t - 144] * ST; }
    else if (t < 152)   { wf[t] = bhh_m[8 + t - 148] * ST; }
    else if (t < 160)   { wf[t] = Wj[t - 152]; }
    else if (t < 164)   { wf[t] = bj[t - 160]; }
    else if (t < 180)   { wf[t] = Wm[t - 164]; }
    else if (t < 184)   { wf[t] = bm[t - 180]; }
    else if (t < 188)   { wf[t] = Wa[t - 184]; }
    else if (t == 188)  { wf[t] = ba[0]; }
}

__global__ __launch_bounds__(256)
void aggreg_policy_dot2(
    const float* __restrict__ x, const void* __restrict__ wsv,
    float* __restrict__ out, int nrows)
{
    const unsigned* WU = (const unsigned*)wsv;
    const float*    WF = (const float*)wsv;
    int b = blockIdx.x * blockDim.x + threadIdx.x;
    if (b >= nrows) return;

    const float2* xr2 = (const float2*)(x + (long)b * 18);
    float xin[18];
    #pragma unroll
    for (int i = 0; i < 9; ++i) { float2 v = xr2[i]; xin[2*i] = v.x; xin[2*i+1] = v.y; }

    // single-copy state, updated in place each iteration
    float hj[7][4], hm[4];
    half2v pj[7][2], pm[2];

    #pragma unroll
    for (int k = 0; k < 7; ++k) {
        #pragma unroll
        for (int u = 0; u < 4; ++u)
            hj[k][u] = fmaf(WF[F_WJ + u*2], xin[4 + k],
                       fmaf(WF[F_WJ + u*2 + 1], xin[11 + k], WF[F_BJ + u]));
        pj[k][0] = pkh(hj[k][0], hj[k][1]);
        pj[k][1] = pkh(hj[k][2], hj[k][3]);
    }
    #pragma unroll
    for (int u = 0; u < 4; ++u) {
        float a = WF[F_BM + u];
        #pragma unroll
        for (int v = 0; v < 4; ++v) a = fmaf(WF[F_WM + u*4 + v], xin[v], a);
        hm[u] = a;
    }
    pm[0] = pkh(hm[0], hm[1]);
    pm[1] = pkh(hm[2], hm[3]);

    #pragma unroll 1   // one copy of the body in I$; trip count 7
    for (int it = 0; it < 7; ++it) {
        // ---- m-GRU: input = OLD hj[0], hidden = OLD hm; commit at end ----
        float hmn[4]; half2v pmn[2];
        {
            float pre[8], inn[4], hn[4];
            #pragma unroll
            for (int g = 0; g < 8; ++g) {
                float a = WF[F_BRZM + g];
                a = fdot2(pj[0][0], ldw(WU, U_PMRZ + g*4 + 0), a);
                a = fdot2(pj[0][1], ldw(WU, U_PMRZ + g*4 + 1), a);
                a = fdot2(pm[0],    ldw(WU, U_PMRZ + g*4 + 2), a);
                a = fdot2(pm[1],    ldw(WU, U_PMRZ + g*4 + 3), a);
                pre[g] = a;
            }
            #pragma unroll
            for (int u = 0; u < 4; ++u) {
                float a = WF[F_BINM + u];
                a = fdot2(pj[0][0], ldw(WU, U_PMNI + u*2 + 0), a);
                a = fdot2(pj[0][1], ldw(WU, U_PMNI + u*2 + 1), a);
                inn[u] = a;
                float c = WF[F_BHNM + u];
                c = fdot2(pm[0], ldw(WU, U_PMNH + u*2 + 0), c);
                c = fdot2(pm[1], ldw(WU, U_PMNH + u*2 + 1), c);
                hn[u] = c;
            }
            gru_out4(pre, inn, hn, hm, hmn);
            pmn[0] = pkh(hmn[0], hmn[1]);
            pmn[1] = pkh(hmn[2], hmn[3]);
        }

        // ---- j-GRU, left to right, in place.
        // cell k reads: opp (OLD pj[k-1]) or OLD pm; pj[k] (not yet replaced);
        // pj[k+1] (not yet reached) -- all OLD values, matching the reference.
        half2v opp[2];
        #pragma unroll
        for (int k = 0; k < 7; ++k) {
            half2v L0 = (k == 0) ? pm[0] : opp[0];
            half2v L1 = (k == 0) ? pm[1] : opp[1];
            half2v H0 = pj[k][0], H1 = pj[k][1];
            float pre[8], inn[4], hn[4];
            #pragma unroll
            for (int g = 0; g < 8; ++g) {
                float a = WF[F_BRZJ + g];
                a = fdot2(L0, ldw(WU, U_PJRZ + g*6 + 0), a);
                a = fdot2(L1, ldw(WU, U_PJRZ + g*6 + 1), a);
                if (k != 6) {   // right neighbor of last cell is zero-pad
                    a = fdot2(pj[k+1][0], ldw(WU, U_PJRZ + g*6 + 2), a);
                    a = fdot2(pj[k+1][1], ldw(WU, U_PJRZ + g*6 + 3), a);
                }
                a = fdot2(H0, ldw(WU, U_PJRZ + g*6 + 4), a);
                a = fdot2(H1, ldw(WU, U_PJRZ + g*6 + 5), a);
                pre[g] = a;
            }
            #pragma unroll
            for (int u = 0; u < 4; ++u) {
                float a = WF[F_BINJ + u];
                a = fdot2(L0, ldw(WU, U_PJNLR + u*4 + 0), a);
                a = fdot2(L1, ldw(WU, U_PJNLR + u*4 + 1), a);
                if (k != 6) {
                    a = fdot2(pj[k+1][0], ldw(WU, U_PJNLR + u*4 + 2), a);
                    a = fdot2(pj[k+1][1], ldw(WU, U_PJNLR + u*4 + 3), a);
                }
                inn[u] = a;
                float c = WF[F_BHNJ + u];
                c = fdot2(H0, ldw(WU, U_PJNH + u*2 + 0), c);
                c = fdot2(H1, ldw(WU, U_PJNH + u*2 + 1), c);
                hn[u] = c;
            }
            float nh[4];
            gru_out4(pre, inn, hn, hj[k], nh);
            // commit: save OLD packed cell k, then overwrite in place
            opp[0] = pj[k][0]; opp[1] = pj[k][1];
            #pragma unroll
            for (int u = 0; u < 4; ++u) hj[k][u] = nh[u];
            pj[k][0] = pkh(nh[0], nh[1]);
            pj[k][1] = pkh(nh[2], nh[3]);
        }

        #pragma unroll
        for (int u = 0; u < 4; ++u) hm[u] = hmn[u];
        pm[0] = pmn[0]; pm[1] = pmn[1];
    }

    float* orow = out + (long)b * 7;
    #pragma unroll
    for (int k = 0; k < 7; ++k) {
        float a = WF[F_BA];
        #pragma unroll
        for (int u = 0; u < 4; ++u) a = fmaf(WF[F_WA + u], hj[k][u], a);
        orow[k] = a;
    }
}

// ---------------- f32 fallback (only if ws too small; never expected) --------
__device__ __forceinline__ float sigmoid_f(float x) {
    return frcp(1.0f + fexp2(-1.44269504088896f * x));
}
__device__ __forceinline__ float tanh_f(float x) {
    float e = fexp2(2.88539008177793f * x);
    return 1.0f - 2.0f * frcp(1.0f + e);
}

__global__ __launch_bounds__(256) void aggreg_policy_fallback(
    const float* __restrict__ x,
    const float* __restrict__ Wj,    const float* __restrict__ bj,
    const float* __restrict__ Wm,    const float* __restrict__ bm,
    const float* __restrict__ Wih_j, const float* __restrict__ Whh_j,
    const float* __restrict__ bih_j, const float* __restrict__ bhh_j,
    const float* __restrict__ Wih_m, const float* __restrict__ Whh_m,
    const float* __restrict__ bih_m, const float* __restrict__ bhh_m,
    const float* __restrict__ Wa,    const float* __restrict__ ba,
    float* __restrict__ out, int nrows)
{
    int b = blockIdx.x * blockDim.x + threadIdx.x;
    if (b >= nrows) return;
    const float* xr = x + (long)b * 18;
    float obs[4], jv[7], jd[7];
    #pragma unroll
    for (int i = 0; i < 4; ++i) obs[i] = xr[i];
    #pragma unroll
    for (int i = 0; i < 7; ++i) jv[i] = xr[4 + i];
    #pragma unroll
    for (int i = 0; i < 7; ++i) jd[i] = xr[11 + i];
    float hj[7][4], hm[4];
    #pragma unroll
    for (int k = 0; k < 7; ++k)
        #pragma unroll
        for (int u = 0; u < 4; ++u)
            hj[k][u] = fmaf(Wj[u*2], jv[k], fmaf(Wj[u*2+1], jd[k], bj[u]));
    #pragma unroll
    for (int u = 0; u < 4; ++u) {
        float a = bm[u];
        #pragma unroll
        for (int v = 0; v < 4; ++v) a = fmaf(Wm[u*4+v], obs[v], a);
        hm[u] = a;
    }
    float bmrz[8], bjrz[8];
    #pragma unroll
    for (int g = 0; g < 8; ++g) { bmrz[g] = bih_m[g]+bhh_m[g]; bjrz[g] = bih_j[g]+bhh_j[g]; }
    #pragma unroll 1
    for (int it = 0; it < 7; ++it) {
        float hmn[4];
        {
            float pre[8], inn[4], hn[4];
            #pragma unroll
            for (int g = 0; g < 8; ++g) {
                float a = bmrz[g];
                #pragma unroll
                for (int v = 0; v < 4; ++v) a = fmaf(Wih_m[g*4+v], hj[0][v], a);
                #pragma unroll
                for (int v = 0; v < 4; ++v) a = fmaf(Whh_m[g*4+v], hm[v], a);
                pre[g] = a;
            }
            #pragma unroll
            for (int u = 0; u < 4; ++u) {
                float a = bih_m[8+u];
                #pragma unroll
                for (int v = 0; v < 4; ++v) a = fmaf(Wih_m[(8+u)*4+v], hj[0][v], a);
                inn[u] = a;
                float c = bhh_m[8+u];
                #pragma unroll
                for (int v = 0; v < 4; ++v) c = fmaf(Whh_m[(8+u)*4+v], hm[v], c);
                hn[u] = c;
            }
            #pragma unroll
            for (int u = 0; u < 4; ++u) {
                float r = sigmoid_f(pre[u]);
                float z = sigmoid_f(pre[4+u]);
                float n = tanh_f(fmaf(r, hn[u], inn[u]));
                hmn[u] = fmaf(z, hm[u]-n, n);
            }
        }
        float nh[7][4];
        #pragma unroll
        for (int k = 0; k < 7; ++k) {
            float L[4], R[4];
            #pragma unroll
            for (int u = 0; u < 4; ++u) {
                L[u] = (k == 0) ? hm[u] : hj[k-1][u];
                R[u] = (k == 6) ? 0.0f  : hj[k+1][u];
            }
            float pre[8], inn[4], hn[4];
            #pragma unroll
            for (int g = 0; g < 8; ++g) {
                float a = bjrz[g];
                #pragma unroll
                for (int v = 0; v < 4; ++v) a = fmaf(Wih_j[g*8+v], L[v], a);
                #pragma unroll
                for (int v = 0; v < 4; ++v) a = fmaf(Wih_j[g*8+4+v], R[v], a);
                #pragma unroll
                for (int v = 0; v < 4; ++v) a = fmaf(Whh_j[g*4+v], hj[k][v], a);
                pre[g] = a;
            }
            #pragma unroll
            for (int u = 0; u < 4; ++u) {
                float a = bih_j[8+u];
                #pragma unroll
                for (int v = 0; v < 4; ++v) a = fmaf(Wih_j[(8+u)*8+v], L[v], a);
                #pragma unroll
                for (int v = 0; v < 4; ++v) a = fmaf(Wih_j[(8+u)*8+4+v], R[v], a);
                inn[u] = a;
                float c = bhh_j[8+u];
                #pragma unroll
                for (int v = 0; v < 4; ++v) c = fmaf(Whh_j[(8+u)*4+v], hj[k][v], c);
                hn[u] = c;
            }
            #pragma unroll
            for (int u = 0; u < 4; ++u) {
                float r = sigmoid_f(pre[u]);
                float z = sigmoid_f(pre[4+u]);
                float n = tanh_f(fmaf(r, hn[u], inn[u]));
                nh[k][u] = fmaf(z, hj[k][u]-n, n);
            }
        }
        #pragma unroll
        for (int k = 0; k < 7; ++k)
            #pragma unroll
            for (int u = 0; u < 4; ++u) hj[k][u] = nh[k][u];
        #pragma unroll
        for (int u = 0; u < 4; ++u) hm[u] = hmn[u];
    }
    float* orow = out + (long)b * 7;
    #pragma unroll
    for (int k = 0; k < 7; ++k) {
        float a = ba[0];
        #pragma unroll
        for (int u = 0; u < 4; ++u) a = fmaf(Wa[u], hj[k][u], a);
        orow[k] = a;
    }
}

extern "C" void kernel_launch(void* const* d_in, const int* in_sizes, int n_in,
                              void* d_out, int out_size, void* d_ws, size_t ws_size,
                              hipStream_t stream) {
    const float* x     = (const float*)d_in[0];
    const float* Wj    = (const float*)d_in[1];
    const float* bj    = (const float*)d_in[2];
    const float* Wm    = (const float*)d_in[3];
    const float* bm    = (const float*)d_in[4];
    const float* Wih_j = (const float*)d_in[5];
    const float* Whh_j = (const float*)d_in[6];
    const float* bih_j = (const float*)d_in[7];
    const float* bhh_j = (const float*)d_in[8];
    const float* Wih_m = (const float*)d_in[9];
    const float* Whh_m = (const float*)d_in[10];
    const float* bih_m = (const float*)d_in[11];
    const float* bhh_m = (const float*)d_in[12];
    const float* Wa    = (const float*)d_in[13];
    const float* ba    = (const float*)d_in[14];
    float* out = (float*)d_out;

    int nrows = in_sizes[0] / 18;
    int block = 256;
    int grid = (nrows + block - 1) / block;

    if (ws_size >= W_TOT2 * sizeof(float)) {
        pack_weights2<<<1, 256, 0, stream>>>(
            Wj, bj, Wm, bm, Wih_j, Whh_j, bih_j, bhh_j,
            Wih_m, Whh_m, bih_m, bhh_m, Wa, ba, d_ws);
        aggreg_policy_dot2<<<grid, block, 0, stream>>>(x, d_ws, out, nrows);
    } else {
        aggreg_policy_fallback<<<grid, block, 0, stream>>>(
            x, Wj, bj, Wm, bm, Wih_j, Whh_j, bih_j, bhh_j,
            Wih_m, Whh_m, bih_m, bhh_m, Wa, ba, out, nrows);
    }
}